// Round 1
// baseline (1807.252 us; speedup 1.0000x reference)
//
#include <hip/hip_runtime.h>

#define HID 256
#define NDRUG 20000
#define NDIS 20000
#define NE 400000
#define NEL 100000
#define NLAYERS 4

// ---------------- init: x_drug = drug_emb[id]; x_dis = dx@Wlin + b + dis_emb[id]
__global__ void k_init(const int* __restrict__ drug_id, const float* __restrict__ drug_emb,
                       const float* __restrict__ dx, const float* __restrict__ Wlin,
                       const float* __restrict__ blin, const int* __restrict__ dis_id,
                       const float* __restrict__ dis_emb,
                       float* __restrict__ x_drug, float* __restrict__ x_dis)
{
    int n = blockIdx.x; int h = threadIdx.x;
    x_drug[(size_t)n * HID + h] = drug_emb[(size_t)drug_id[n] * HID + h];
    __shared__ float xr[10];
    if (h < 10) xr[h] = dx[n * 10 + h];
    __syncthreads();
    float acc = blin[h] + dis_emb[(size_t)dis_id[n] * HID + h];
#pragma unroll
    for (int k = 0; k < 10; ++k) acc += xr[k] * Wlin[k * HID + h];
    x_dis[(size_t)n * HID + h] = acc;
}

// ---------------- CSR build
__global__ void k_count(const int* __restrict__ dst, int n, int* __restrict__ cnt)
{
    int i = blockIdx.x * 256 + threadIdx.x;
    if (i < n) atomicAdd(&cnt[dst[i]], 1);
}

// 2 blocks: block 0 scans A, block 1 scans B. Exclusive scan -> offsets[n+1].
__global__ void k_scan(const int* __restrict__ cntA, int* __restrict__ offA,
                       const int* __restrict__ cntB, int* __restrict__ offB, int n)
{
    const int* cnt = blockIdx.x ? cntB : cntA;
    int* off = blockIdx.x ? offB : offA;
    __shared__ int sm[1024];
    __shared__ int carry;
    int tid = threadIdx.x;
    if (tid == 0) { carry = 0; off[0] = 0; }
    __syncthreads();
    for (int base = 0; base < n; base += 1024) {
        int i = base + tid;
        int v = (i < n) ? cnt[i] : 0;
        sm[tid] = v;
        __syncthreads();
        for (int o = 1; o < 1024; o <<= 1) {
            int t = (tid >= o) ? sm[tid - o] : 0;
            __syncthreads();
            sm[tid] += t;
            __syncthreads();
        }
        if (i < n) off[i + 1] = carry + sm[tid];
        int tot = sm[1023];
        __syncthreads();
        if (tid == 0) carry += tot;
        __syncthreads();
    }
}

__global__ void k_fill(const int* __restrict__ src, const int* __restrict__ dst, int n,
                       const int* __restrict__ off, int* __restrict__ cur, int* __restrict__ out)
{
    int i = blockIdx.x * 256 + threadIdx.x;
    if (i < n) {
        int d = dst[i];
        int p = atomicAdd(&cur[d], 1);
        out[off[d] + p] = src[i];
    }
}

// ---------------- mean aggregation: one block per destination node, thread = h dim
__global__ void k_agg(const float* __restrict__ xsrc, const int* __restrict__ off,
                      const int* __restrict__ csr, float* __restrict__ out)
{
    int d = blockIdx.x;
    int h = threadIdx.x;
    int s = off[d], e = off[d + 1];
    float acc = 0.0f;
    int i = s;
    for (; i + 4 <= e; i += 4) {
        int n0 = csr[i], n1 = csr[i + 1], n2 = csr[i + 2], n3 = csr[i + 3];
        acc += xsrc[(size_t)n0 * HID + h];
        acc += xsrc[(size_t)n1 * HID + h];
        acc += xsrc[(size_t)n2 * HID + h];
        acc += xsrc[(size_t)n3 * HID + h];
    }
    for (; i < e; ++i) acc += xsrc[(size_t)csr[i] * HID + h];
    float c = (float)(e - s);
    out[(size_t)d * HID + h] = acc / fmaxf(c, 1.0f);
}

// ---------------- fused dual GEMM: C = act(A@W1 + X@W2 + b), all K=N=256
__global__ __launch_bounds__(256) void k_gemm2(
    const float* __restrict__ A, const float* __restrict__ W1,
    const float* __restrict__ X, const float* __restrict__ W2,
    const float* __restrict__ bias, float* __restrict__ C,
    int M, int relu)
{
    __shared__ float As[32][68];
    __shared__ float Bs[32][68];
    const int bm = blockIdx.x * 64;
    const int bn = blockIdx.y * 64;
    const int tid = threadIdx.x;
    const int tx = tid & 15, ty = tid >> 4;
    float acc[4][4] = {};

    for (int pass = 0; pass < 2; ++pass) {
        const float* Ap = pass ? X : A;
        const float* Wp = pass ? W2 : W1;
        for (int k0 = 0; k0 < HID; k0 += 32) {
#pragma unroll
            for (int l = 0; l < 2; ++l) {
                int id2 = tid + l * 256;
                int row = id2 >> 3, c4 = (id2 & 7) << 2;
                float4 v = make_float4(0.f, 0.f, 0.f, 0.f);
                if (bm + row < M) v = *(const float4*)(Ap + (size_t)(bm + row) * HID + k0 + c4);
                As[c4 + 0][row] = v.x; As[c4 + 1][row] = v.y;
                As[c4 + 2][row] = v.z; As[c4 + 3][row] = v.w;
            }
#pragma unroll
            for (int l = 0; l < 2; ++l) {
                int id2 = tid + l * 256;
                int row = id2 >> 4, c4 = (id2 & 15) << 2;
                *(float4*)&Bs[row][c4] = *(const float4*)(Wp + (size_t)(k0 + row) * HID + bn + c4);
            }
            __syncthreads();
#pragma unroll
            for (int k = 0; k < 32; ++k) {
                float4 av = *(const float4*)&As[k][ty << 2];
                float4 bv = *(const float4*)&Bs[k][tx << 2];
                acc[0][0] += av.x * bv.x; acc[0][1] += av.x * bv.y; acc[0][2] += av.x * bv.z; acc[0][3] += av.x * bv.w;
                acc[1][0] += av.y * bv.x; acc[1][1] += av.y * bv.y; acc[1][2] += av.y * bv.z; acc[1][3] += av.y * bv.w;
                acc[2][0] += av.z * bv.x; acc[2][1] += av.z * bv.y; acc[2][2] += av.z * bv.z; acc[2][3] += av.z * bv.w;
                acc[3][0] += av.w * bv.x; acc[3][1] += av.w * bv.y; acc[3][2] += av.w * bv.z; acc[3][3] += av.w * bv.w;
            }
            __syncthreads();
        }
    }
#pragma unroll
    for (int i = 0; i < 4; ++i) {
        int r = bm + (ty << 2) + i;
        if (r < M) {
#pragma unroll
            for (int j = 0; j < 4; ++j) {
                int c = bn + (tx << 2) + j;
                float v = acc[i][j] + bias[c];
                if (relu) v = fmaxf(v, 0.0f);
                C[(size_t)r * HID + c] = v;
            }
        }
    }
}

// ---------------- generic single GEMM: C = act(A@W + b). A:[M,K] stride K, W:[K,N], C:[M,N]
// N multiple of 64 (grid.y = N/64), K multiple of 32.
__global__ __launch_bounds__(256) void k_gemm1(
    const float* __restrict__ A, const float* __restrict__ W,
    const float* __restrict__ bias, float* __restrict__ C,
    int M, int N, int K, int relu)
{
    __shared__ float As[32][68];
    __shared__ float Bs[32][68];
    const int bm = blockIdx.x * 64;
    const int bn = blockIdx.y * 64;
    const int tid = threadIdx.x;
    const int tx = tid & 15, ty = tid >> 4;
    float acc[4][4] = {};

    for (int k0 = 0; k0 < K; k0 += 32) {
#pragma unroll
        for (int l = 0; l < 2; ++l) {
            int id2 = tid + l * 256;
            int row = id2 >> 3, c4 = (id2 & 7) << 2;
            float4 v = make_float4(0.f, 0.f, 0.f, 0.f);
            if (bm + row < M) v = *(const float4*)(A + (size_t)(bm + row) * K + k0 + c4);
            As[c4 + 0][row] = v.x; As[c4 + 1][row] = v.y;
            As[c4 + 2][row] = v.z; As[c4 + 3][row] = v.w;
        }
#pragma unroll
        for (int l = 0; l < 2; ++l) {
            int id2 = tid + l * 256;
            int row = id2 >> 4, c4 = (id2 & 15) << 2;
            *(float4*)&Bs[row][c4] = *(const float4*)(W + (size_t)(k0 + row) * N + bn + c4);
        }
        __syncthreads();
#pragma unroll
        for (int k = 0; k < 32; ++k) {
            float4 av = *(const float4*)&As[k][ty << 2];
            float4 bv = *(const float4*)&Bs[k][tx << 2];
            acc[0][0] += av.x * bv.x; acc[0][1] += av.x * bv.y; acc[0][2] += av.x * bv.z; acc[0][3] += av.x * bv.w;
            acc[1][0] += av.y * bv.x; acc[1][1] += av.y * bv.y; acc[1][2] += av.y * bv.z; acc[1][3] += av.y * bv.w;
            acc[2][0] += av.z * bv.x; acc[2][1] += av.z * bv.y; acc[2][2] += av.z * bv.z; acc[2][3] += av.z * bv.w;
            acc[3][0] += av.w * bv.x; acc[3][1] += av.w * bv.y; acc[3][2] += av.w * bv.z; acc[3][3] += av.w * bv.w;
        }
        __syncthreads();
    }
#pragma unroll
    for (int i = 0; i < 4; ++i) {
        int r = bm + (ty << 2) + i;
        if (r < M) {
#pragma unroll
            for (int j = 0; j < 4; ++j) {
                int c = bn + (tx << 2) + j;
                float v = acc[i][j] + bias[c];
                if (relu) v = fmaxf(v, 0.0f);
                C[(size_t)r * N + c] = v;
            }
        }
    }
}

// ---------------- fc1 with fused gather: A row r = concat(xdrug[ia[row0+r]], xdis[ib[row0+r]])
// K=512, N=256, relu always.
__global__ __launch_bounds__(256) void k_gemm_g(
    const float* __restrict__ xdrug, const float* __restrict__ xdis,
    const int* __restrict__ ia, const int* __restrict__ ib, int row0, int M,
    const float* __restrict__ W, const float* __restrict__ bias,
    float* __restrict__ C)
{
    __shared__ float As[32][68];
    __shared__ float Bs[32][68];
    const int bm = blockIdx.x * 64;
    const int bn = blockIdx.y * 64;
    const int tid = threadIdx.x;
    const int tx = tid & 15, ty = tid >> 4;
    float acc[4][4] = {};

    for (int k0 = 0; k0 < 512; k0 += 32) {
        const float* xs = (k0 < 256) ? xdrug : xdis;
        const int* idxp = (k0 < 256) ? ia : ib;
        int kk = k0 & 255;
#pragma unroll
        for (int l = 0; l < 2; ++l) {
            int id2 = tid + l * 256;
            int row = id2 >> 3, c4 = (id2 & 7) << 2;
            float4 v = make_float4(0.f, 0.f, 0.f, 0.f);
            int r = bm + row;
            if (r < M) {
                int nd = idxp[row0 + r];
                v = *(const float4*)(xs + (size_t)nd * HID + kk + c4);
            }
            As[c4 + 0][row] = v.x; As[c4 + 1][row] = v.y;
            As[c4 + 2][row] = v.z; As[c4 + 3][row] = v.w;
        }
#pragma unroll
        for (int l = 0; l < 2; ++l) {
            int id2 = tid + l * 256;
            int row = id2 >> 4, c4 = (id2 & 15) << 2;
            *(float4*)&Bs[row][c4] = *(const float4*)(W + (size_t)(k0 + row) * 256 + bn + c4);
        }
        __syncthreads();
#pragma unroll
        for (int k = 0; k < 32; ++k) {
            float4 av = *(const float4*)&As[k][ty << 2];
            float4 bv = *(const float4*)&Bs[k][tx << 2];
            acc[0][0] += av.x * bv.x; acc[0][1] += av.x * bv.y; acc[0][2] += av.x * bv.z; acc[0][3] += av.x * bv.w;
            acc[1][0] += av.y * bv.x; acc[1][1] += av.y * bv.y; acc[1][2] += av.y * bv.z; acc[1][3] += av.y * bv.w;
            acc[2][0] += av.z * bv.x; acc[2][1] += av.z * bv.y; acc[2][2] += av.z * bv.z; acc[2][3] += av.z * bv.w;
            acc[3][0] += av.w * bv.x; acc[3][1] += av.w * bv.y; acc[3][2] += av.w * bv.z; acc[3][3] += av.w * bv.w;
        }
        __syncthreads();
    }
#pragma unroll
    for (int i = 0; i < 4; ++i) {
        int r = bm + (ty << 2) + i;
        if (r < M) {
#pragma unroll
            for (int j = 0; j < 4; ++j) {
                int c = bn + (tx << 2) + j;
                float v = acc[i][j] + bias[c];
                C[(size_t)r * 256 + c] = fmaxf(v, 0.0f);
            }
        }
    }
}

// ---------------- fc4: out[r] = dot(e3[r,:64], w) + b ; one wave per row
__global__ void k_fc4(const float* __restrict__ E3, const float* __restrict__ w,
                      const float* __restrict__ b, float* __restrict__ out, int M)
{
    int lane = threadIdx.x & 63;
    int row = blockIdx.x * 4 + (threadIdx.x >> 6);
    if (row >= M) return;
    float v = E3[(size_t)row * 64 + lane] * w[lane];
#pragma unroll
    for (int o = 32; o > 0; o >>= 1) v += __shfl_down(v, o);
    if (lane == 0) out[row] = v + b[0];
}

extern "C" void kernel_launch(void* const* d_in, const int* in_sizes, int n_in,
                              void* d_out, int out_size, void* d_ws, size_t ws_size,
                              hipStream_t stream)
{
    const int*   drug_id   = (const int*)d_in[0];
    const float* disease_x = (const float*)d_in[1];
    const int*   dis_id    = (const int*)d_in[2];
    const int*   e_mt      = (const int*)d_in[3];
    const int*   e_rev     = (const int*)d_in[4];
    const int*   e_lbl     = (const int*)d_in[5];
    const float* drug_emb  = (const float*)d_in[6];
    const float* dis_emb   = (const float*)d_in[7];
    const float* lin_w     = (const float*)d_in[8];
    const float* lin_b     = (const float*)d_in[9];
    const float* Wl_mt     = (const float*)d_in[10];
    const float* bl_mt     = (const float*)d_in[11];
    const float* Wr_mt     = (const float*)d_in[12];
    const float* Wl_rev    = (const float*)d_in[13];
    const float* bl_rev    = (const float*)d_in[14];
    const float* Wr_rev    = (const float*)d_in[15];
    const float* fc1_w = (const float*)d_in[16]; const float* fc1_b = (const float*)d_in[17];
    const float* fc2_w = (const float*)d_in[18]; const float* fc2_b = (const float*)d_in[19];
    const float* fc3_w = (const float*)d_in[20]; const float* fc3_b = (const float*)d_in[21];
    const float* fc4_w = (const float*)d_in[22]; const float* fc4_b = (const float*)d_in[23];
    float* out = (float*)d_out;

    float* ws = (float*)d_ws;
    const size_t NH = (size_t)NDRUG * HID;    // 5,120,000 floats
    float* xA_dis  = ws;
    float* xA_drug = ws + NH;
    float* xB_dis  = ws + 2 * NH;
    float* xB_drug = ws + 3 * NH;
    float* agg_dis  = ws + 4 * NH;
    float* agg_drug = ws + 5 * NH;
    int* ip = (int*)(ws + 6 * NH);
    int* cnt_dis  = ip;                 // 20000
    int* cnt_drug = ip + 20000;         // 20000
    int* cur_dis  = ip + 40000;         // 20000
    int* cur_drug = ip + 60000;         // 20000
    int* off_dis  = ip + 80000;         // 20001
    int* off_drug = ip + 100001;        // 20001
    int* csr_mt   = ip + 120002;        // 400000 (drug srcs grouped by disease dst)
    int* csr_rev  = ip + 520002;        // 400000 (disease srcs grouped by drug dst)

    hipMemsetAsync(ip, 0, 80000 * sizeof(int), stream);
    k_init<<<NDRUG, HID, 0, stream>>>(drug_id, drug_emb, disease_x, lin_w, lin_b,
                                      dis_id, dis_emb, xA_drug, xA_dis);
    int nbE = (NE + 255) / 256;
    k_count<<<nbE, 256, 0, stream>>>(e_mt + NE, NE, cnt_dis);
    k_count<<<nbE, 256, 0, stream>>>(e_rev + NE, NE, cnt_drug);
    k_scan<<<2, 1024, 0, stream>>>(cnt_dis, off_dis, cnt_drug, off_drug, 20000);
    k_fill<<<nbE, 256, 0, stream>>>(e_mt, e_mt + NE, NE, off_dis, cur_dis, csr_mt);
    k_fill<<<nbE, 256, 0, stream>>>(e_rev, e_rev + NE, NE, off_drug, cur_drug, csr_rev);

    float* xd = xA_dis;  float* xg = xA_drug;   // current layer input
    float* td = xB_dis;  float* tg = xB_drug;   // layer output
    dim3 g2((NDRUG + 63) / 64, 4);
    for (int l = 0; l < NLAYERS; ++l) {
        k_agg<<<NDIS, 256, 0, stream>>>(xg, off_dis, csr_mt, agg_dis);
        k_agg<<<NDRUG, 256, 0, stream>>>(xd, off_drug, csr_rev, agg_drug);
        int relu = (l < NLAYERS - 1) ? 1 : 0;
        k_gemm2<<<g2, 256, 0, stream>>>(agg_dis, Wl_mt + (size_t)l * HID * HID,
                                        xd, Wr_mt + (size_t)l * HID * HID,
                                        bl_mt + l * HID, td, NDIS, relu);
        k_gemm2<<<g2, 256, 0, stream>>>(agg_drug, Wl_rev + (size_t)l * HID * HID,
                                        xg, Wr_rev + (size_t)l * HID * HID,
                                        bl_rev + l * HID, tg, NDRUG, relu);
        float* t;
        t = xd; xd = td; td = t;
        t = xg; xg = tg; tg = t;
    }

    // classifier in chunks; e-buffers alias the (now dead) agg buffers
    float* e1 = agg_dis;                 // [20000,256]
    float* e2 = agg_drug;                // [20000,128]
    float* e3 = agg_drug + 20000 * 128;  // [20000,64]
    for (int c = 0; c < NEL; c += 20000) {
        int Mc = (NEL - c < 20000) ? (NEL - c) : 20000;
        int gx = (Mc + 63) / 64;
        k_gemm_g<<<dim3(gx, 4), 256, 0, stream>>>(xg, xd, e_lbl, e_lbl + NEL, c, Mc,
                                                  fc1_w, fc1_b, e1);
        k_gemm1<<<dim3(gx, 2), 256, 0, stream>>>(e1, fc2_w, fc2_b, e2, Mc, 128, 256, 1);
        k_gemm1<<<dim3(gx, 1), 256, 0, stream>>>(e2, fc3_w, fc3_b, e3, Mc, 64, 128, 1);
        k_fc4<<<(Mc + 3) / 4, 256, 0, stream>>>(e3, fc4_w, fc4_b, out + c, Mc);
    }
}

// Round 3
// 1121.266 us; speedup vs baseline: 1.6118x; 1.6118x over previous
//
#include <hip/hip_runtime.h>

#define HID 256
#define NDRUG 20000
#define NDIS 20000
#define NE 400000
#define NEL 100000
#define NLAYERS 4

typedef float f32x4 __attribute__((ext_vector_type(4)));
typedef short s16x8 __attribute__((ext_vector_type(8)));
typedef unsigned short ushort_t;
typedef unsigned int uint_t;

// ---- bf16 helpers (round-to-nearest-even) ----
__device__ __forceinline__ ushort_t f2bf(float f) {
    uint_t u = __float_as_uint(f);
    u += 0x7fffu + ((u >> 16) & 1u);
    return (ushort_t)(u >> 16);
}
__device__ __forceinline__ float bf2f(ushort_t h) {
    return __uint_as_float(((uint_t)h) << 16);
}

// ---- async global->LDS, 16B per lane; lptr must be wave-uniform base ----
__device__ __forceinline__ void gl_lds16(const void* g, void* l) {
    __builtin_amdgcn_global_load_lds(
        (const __attribute__((address_space(1))) void*)g,
        (__attribute__((address_space(3))) void*)l, 16, 0, 0);
}

// ---------------- init: x_drug = drug_emb[id]; x_dis = dx@Wlin + b + dis_emb[id]
// outputs split hi/lo bf16
__global__ void k_init(const int* __restrict__ drug_id, const float* __restrict__ drug_emb,
                       const float* __restrict__ dx, const float* __restrict__ Wlin,
                       const float* __restrict__ blin, const int* __restrict__ dis_id,
                       const float* __restrict__ dis_emb,
                       ushort_t* __restrict__ xh_drug, ushort_t* __restrict__ xl_drug,
                       ushort_t* __restrict__ xh_dis, ushort_t* __restrict__ xl_dis)
{
    int n = blockIdx.x; int h = threadIdx.x;
    size_t o = (size_t)n * HID + h;
    float vd = drug_emb[(size_t)drug_id[n] * HID + h];
    ushort_t hd = f2bf(vd);
    xh_drug[o] = hd;
    xl_drug[o] = f2bf(vd - bf2f(hd));

    __shared__ float xr[10];
    if (h < 10) xr[h] = dx[n * 10 + h];
    __syncthreads();
    float acc = blin[h] + dis_emb[(size_t)dis_id[n] * HID + h];
#pragma unroll
    for (int k = 0; k < 10; ++k) acc += xr[k] * Wlin[k * HID + h];
    ushort_t hs = f2bf(acc);
    xh_dis[o] = hs;
    xl_dis[o] = f2bf(acc - bf2f(hs));
}

// ---------------- weight transpose + hi/lo split: W[K][N] f32 -> Wt_h/Wt_l [N][K] bf16
// grid: (N/64, K/64), block 256
__global__ void k_trans(const float* __restrict__ W, ushort_t* __restrict__ th,
                        ushort_t* __restrict__ tl, int K, int N)
{
    __shared__ float sm[64][65];
    int n0 = blockIdx.x * 64, k0 = blockIdx.y * 64;
    int tx = threadIdx.x & 63, ty = threadIdx.x >> 6;
    for (int r = ty; r < 64; r += 4) sm[r][tx] = W[(size_t)(k0 + r) * N + n0 + tx];
    __syncthreads();
    for (int r = ty; r < 64; r += 4) {
        float v = sm[tx][r];
        ushort_t h = f2bf(v);
        float lo = v - bf2f(h);
        size_t o = (size_t)(n0 + r) * K + k0 + tx;
        th[o] = h;
        tl[o] = f2bf(lo);
    }
}

// ---------------- CSR build
__global__ void k_count(const int* __restrict__ dst, int n, int* __restrict__ cnt)
{
    int i = blockIdx.x * 256 + threadIdx.x;
    if (i < n) atomicAdd(&cnt[dst[i]], 1);
}

__global__ void k_scan(const int* __restrict__ cntA, int* __restrict__ offA,
                       const int* __restrict__ cntB, int* __restrict__ offB, int n)
{
    const int* cnt = blockIdx.x ? cntB : cntA;
    int* off = blockIdx.x ? offB : offA;
    __shared__ int sm[1024];
    __shared__ int carry;
    int tid = threadIdx.x;
    if (tid == 0) { carry = 0; off[0] = 0; }
    __syncthreads();
    for (int base = 0; base < n; base += 1024) {
        int i = base + tid;
        int v = (i < n) ? cnt[i] : 0;
        sm[tid] = v;
        __syncthreads();
        for (int o = 1; o < 1024; o <<= 1) {
            int t = (tid >= o) ? sm[tid - o] : 0;
            __syncthreads();
            sm[tid] += t;
            __syncthreads();
        }
        if (i < n) off[i + 1] = carry + sm[tid];
        int tot = sm[1023];
        __syncthreads();
        if (tid == 0) carry += tot;
        __syncthreads();
    }
}

__global__ void k_fill(const int* __restrict__ src, const int* __restrict__ dst, int n,
                       const int* __restrict__ off, int* __restrict__ cur, int* __restrict__ out)
{
    int i = blockIdx.x * 256 + threadIdx.x;
    if (i < n) {
        int d = dst[i];
        int p = atomicAdd(&cur[d], 1);
        out[off[d] + p] = src[i];
    }
}

// ---------------- mean aggregation from bf16-hi x; writes agg hi/lo bf16
// block = dst node, 128 threads, each handles 2 h-dims via packed uint
__global__ void k_agg(const uint_t* __restrict__ x32, const int* __restrict__ off,
                      const int* __restrict__ csr, uint_t* __restrict__ aggh,
                      uint_t* __restrict__ aggl)
{
    int d = blockIdx.x;
    int t = threadIdx.x;       // 0..127
    int s = off[d], e = off[d + 1];
    float a0 = 0.f, a1 = 0.f;
    int i = s;
    for (; i + 4 <= e; i += 4) {
        int n0 = csr[i], n1 = csr[i + 1], n2 = csr[i + 2], n3 = csr[i + 3];
        uint_t v0 = x32[(size_t)n0 * 128 + t];
        uint_t v1 = x32[(size_t)n1 * 128 + t];
        uint_t v2 = x32[(size_t)n2 * 128 + t];
        uint_t v3 = x32[(size_t)n3 * 128 + t];
        a0 += bf2f(v0 & 0xffff) + bf2f(v1 & 0xffff) + bf2f(v2 & 0xffff) + bf2f(v3 & 0xffff);
        a1 += bf2f(v0 >> 16) + bf2f(v1 >> 16) + bf2f(v2 >> 16) + bf2f(v3 >> 16);
    }
    for (; i < e; ++i) {
        uint_t v = x32[(size_t)csr[i] * 128 + t];
        a0 += bf2f(v & 0xffff);
        a1 += bf2f(v >> 16);
    }
    float inv = 1.f / fmaxf((float)(e - s), 1.f);
    a0 *= inv; a1 *= inv;
    ushort_t h0 = f2bf(a0), h1 = f2bf(a1);
    aggh[(size_t)d * 128 + t] = (uint_t)h0 | ((uint_t)h1 << 16);
    ushort_t l0 = f2bf(a0 - bf2f(h0)), l1 = f2bf(a1 - bf2f(h1));
    aggl[(size_t)d * 128 + t] = (uint_t)l0 | ((uint_t)l1 << 16);
}

// ---------------- MFMA GEMM, bf16 hi/lo 3-pass split precision
// C = act( sum_p A_p @ W_p + bias ), P passes of K=Kp each.
// A matrices: [M][Kp] bf16 (hi & lo). W transposed: Wt[n][wstride] bf16; pass p
// uses row offset woff_p (0 / w1off). Gather (G=1): A row r = src[idx[row0+r]].
// Tile: BM=128, BN=64, BK=32; 256 threads = 4 waves, wave w owns rows w*32..+31.
// Output: hi/lo bf16 (Ch/Cl) or f32 (Cf) with stride N.
template<int P, int G>
__global__ __launch_bounds__(256) void k_mgemm(
    const ushort_t* __restrict__ A0h, const ushort_t* __restrict__ A0l,
    const ushort_t* __restrict__ A1h, const ushort_t* __restrict__ A1l,
    const int* __restrict__ ia, const int* __restrict__ ib, int row0,
    const ushort_t* __restrict__ W0h, const ushort_t* __restrict__ W0l,
    const ushort_t* __restrict__ W1h, const ushort_t* __restrict__ W1l,
    int wstride, int w1off,
    const float* __restrict__ bias, int M, int N, int Kp, int relu,
    ushort_t* __restrict__ Ch, ushort_t* __restrict__ Cl, float* __restrict__ Cf)
{
    __shared__ __align__(16) ushort_t Ah_s[128 * 32];
    __shared__ __align__(16) ushort_t Al_s[128 * 32];
    __shared__ __align__(16) ushort_t Bh_s[64 * 32];
    __shared__ __align__(16) ushort_t Bl_s[64 * 32];

    const int tid = threadIdx.x;
    const int lane = tid & 63;
    const int wv = tid >> 6;
    const int bm = blockIdx.x * 128;
    const int bn = blockIdx.y * 64;

    // staging geometry: 16B chunks; A tile 128x32 = 512 chunks (2 calls),
    // B tile 64x32 = 256 chunks (1 call). chunk c -> row c>>2, koff (c&3)*8.
    const int cA0 = wv * 64 + lane;
    const int cA1 = 256 + cA0;
    const int rA0 = cA0 >> 2, sA0 = (cA0 & 3) * 8;
    const int rA1 = cA1 >> 2, sA1 = (cA1 & 3) * 8;
    const int colB = cA0 >> 2, sB = (cA0 & 3) * 8;

    f32x4 acc[2][4] = {};

    for (int p = 0; p < P; ++p) {
        const ushort_t* Ah = p ? A1h : A0h;
        const ushort_t* Al = p ? A1l : A0l;
        const ushort_t* Wh = p ? W1h : W0h;
        const ushort_t* Wl = p ? W1l : W0l;
        const int woff = p ? w1off : 0;

        // per-pass A row indices (k-independent)
        int r0 = bm + rA0; if (r0 > M - 1) r0 = M - 1;
        int r1 = bm + rA1; if (r1 > M - 1) r1 = M - 1;
        if (G) {
            const int* idx = p ? ib : ia;
            r0 = idx[row0 + r0];
            r1 = idx[row0 + r1];
        }
        const size_t a0base = (size_t)r0 * Kp + sA0;
        const size_t a1base = (size_t)r1 * Kp + sA1;
        const size_t bbase = (size_t)(bn + colB) * wstride + woff + sB;

        for (int k0 = 0; k0 < Kp; k0 += 32) {
            gl_lds16(Ah + a0base + k0, &Ah_s[wv * 512]);
            gl_lds16(Ah + a1base + k0, &Ah_s[2048 + wv * 512]);
            gl_lds16(Al + a0base + k0, &Al_s[wv * 512]);
            gl_lds16(Al + a1base + k0, &Al_s[2048 + wv * 512]);
            gl_lds16(Wh + bbase + k0, &Bh_s[wv * 512]);
            gl_lds16(Wl + bbase + k0, &Bl_s[wv * 512]);
            __syncthreads();

            const int arow = lane & 15;
            const int k8 = (lane >> 4) * 8;
            const int aoff = (wv * 32 + arow) * 32 + k8;
            const int boff = arow * 32 + k8;
            s16x8 a0 = *(const s16x8*)&Ah_s[aoff];
            s16x8 a1 = *(const s16x8*)&Ah_s[aoff + 512];
            s16x8 a0l = *(const s16x8*)&Al_s[aoff];
            s16x8 a1l = *(const s16x8*)&Al_s[aoff + 512];
#pragma unroll
            for (int ni = 0; ni < 4; ++ni) {
                s16x8 b = *(const s16x8*)&Bh_s[boff + ni * 512];
                s16x8 bl = *(const s16x8*)&Bl_s[boff + ni * 512];
                acc[0][ni] = __builtin_amdgcn_mfma_f32_16x16x32_bf16(a0, b, acc[0][ni], 0, 0, 0);
                acc[1][ni] = __builtin_amdgcn_mfma_f32_16x16x32_bf16(a1, b, acc[1][ni], 0, 0, 0);
                acc[0][ni] = __builtin_amdgcn_mfma_f32_16x16x32_bf16(a0l, b, acc[0][ni], 0, 0, 0);
                acc[1][ni] = __builtin_amdgcn_mfma_f32_16x16x32_bf16(a1l, b, acc[1][ni], 0, 0, 0);
                acc[0][ni] = __builtin_amdgcn_mfma_f32_16x16x32_bf16(a0, bl, acc[0][ni], 0, 0, 0);
                acc[1][ni] = __builtin_amdgcn_mfma_f32_16x16x32_bf16(a1, bl, acc[1][ni], 0, 0, 0);
            }
            __syncthreads();
        }
    }

    // epilogue: C/D layout col=lane&15, row=(lane>>4)*4+j
    const int colC = lane & 15;
    const int rbase = (lane >> 4) * 4;
#pragma unroll
    for (int mi = 0; mi < 2; ++mi) {
#pragma unroll
        for (int j = 0; j < 4; ++j) {
            int r = bm + wv * 32 + mi * 16 + rbase + j;
            if (r < M) {
#pragma unroll
                for (int ni = 0; ni < 4; ++ni) {
                    int c = bn + ni * 16 + colC;
                    float v = acc[mi][ni][j] + bias[c];
                    if (relu) v = fmaxf(v, 0.f);
                    if (Cf) {
                        Cf[(size_t)r * N + c] = v;
                    } else {
                        ushort_t h = f2bf(v);
                        Ch[(size_t)r * N + c] = h;
                        Cl[(size_t)r * N + c] = f2bf(v - bf2f(h));
                    }
                }
            }
        }
    }
}

// ---------------- fc4: out[r] = dot(e3[r,:64], w) + b
__global__ void k_fc4(const float* __restrict__ E3, const float* __restrict__ w,
                      const float* __restrict__ b, float* __restrict__ out, int M)
{
    int lane = threadIdx.x & 63;
    int row = blockIdx.x * 4 + (threadIdx.x >> 6);
    if (row >= M) return;
    float v = E3[(size_t)row * 64 + lane] * w[lane];
#pragma unroll
    for (int o = 32; o > 0; o >>= 1) v += __shfl_down(v, o);
    if (lane == 0) out[row] = v + b[0];
}

extern "C" void kernel_launch(void* const* d_in, const int* in_sizes, int n_in,
                              void* d_out, int out_size, void* d_ws, size_t ws_size,
                              hipStream_t stream)
{
    const int*   drug_id   = (const int*)d_in[0];
    const float* disease_x = (const float*)d_in[1];
    const int*   dis_id    = (const int*)d_in[2];
    const int*   e_mt      = (const int*)d_in[3];
    const int*   e_rev     = (const int*)d_in[4];
    const int*   e_lbl     = (const int*)d_in[5];
    const float* drug_emb  = (const float*)d_in[6];
    const float* dis_emb   = (const float*)d_in[7];
    const float* lin_w     = (const float*)d_in[8];
    const float* lin_b     = (const float*)d_in[9];
    const float* Wl_mt     = (const float*)d_in[10];
    const float* bl_mt     = (const float*)d_in[11];
    const float* Wr_mt     = (const float*)d_in[12];
    const float* Wl_rev    = (const float*)d_in[13];
    const float* bl_rev    = (const float*)d_in[14];
    const float* Wr_rev    = (const float*)d_in[15];
    const float* fc1_w = (const float*)d_in[16]; const float* fc1_b = (const float*)d_in[17];
    const float* fc2_w = (const float*)d_in[18]; const float* fc2_b = (const float*)d_in[19];
    const float* fc3_w = (const float*)d_in[20]; const float* fc3_b = (const float*)d_in[21];
    const float* fc4_w = (const float*)d_in[22]; const float* fc4_b = (const float*)d_in[23];
    float* out = (float*)d_out;

    // ---- workspace layout ----
    char* base = (char*)d_ws;
    size_t o = 0;
    auto alloc = [&](size_t bytes) { char* r = base + o; o += (bytes + 255) & ~(size_t)255; return r; };
    const size_t XB = (size_t)20000 * 256 * 2;   // one bf16 activation plane

    ushort_t* xh_dis  = (ushort_t*)alloc(XB);
    ushort_t* xl_dis  = (ushort_t*)alloc(XB);
    ushort_t* xh_drug = (ushort_t*)alloc(XB);
    ushort_t* xl_drug = (ushort_t*)alloc(XB);
    ushort_t* yh_dis  = (ushort_t*)alloc(XB);
    ushort_t* yl_dis  = (ushort_t*)alloc(XB);
    ushort_t* yh_drug = (ushort_t*)alloc(XB);
    ushort_t* yl_drug = (ushort_t*)alloc(XB);
    ushort_t* aggh    = (ushort_t*)alloc(XB);
    ushort_t* aggl    = (ushort_t*)alloc(XB);
    const size_t WB = (size_t)4 * 256 * 256 * 2; // 4-layer weight family, bf16
    ushort_t* wlmt_h  = (ushort_t*)alloc(WB); ushort_t* wlmt_l  = (ushort_t*)alloc(WB);
    ushort_t* wrmt_h  = (ushort_t*)alloc(WB); ushort_t* wrmt_l  = (ushort_t*)alloc(WB);
    ushort_t* wlrev_h = (ushort_t*)alloc(WB); ushort_t* wlrev_l = (ushort_t*)alloc(WB);
    ushort_t* wrrev_h = (ushort_t*)alloc(WB); ushort_t* wrrev_l = (ushort_t*)alloc(WB);
    ushort_t* fc1t_h  = (ushort_t*)alloc(512 * 256 * 2); ushort_t* fc1t_l = (ushort_t*)alloc(512 * 256 * 2);
    ushort_t* fc2t_h  = (ushort_t*)alloc(256 * 128 * 2); ushort_t* fc2t_l = (ushort_t*)alloc(256 * 128 * 2);
    ushort_t* fc3t_h  = (ushort_t*)alloc(128 * 64 * 2);  ushort_t* fc3t_l = (ushort_t*)alloc(128 * 64 * 2);
    // CSR counters/cursors: ONE contiguous block so a single memset covers it
    int* cnts     = (int*)alloc(80000 * 4);
    int* cnt_dis  = cnts;
    int* cnt_drug = cnts + 20000;
    int* cur_dis  = cnts + 40000;
    int* cur_drug = cnts + 60000;
    int* off_dis  = (int*)alloc(20004 * 4);
    int* off_drug = (int*)alloc(20004 * 4);
    int* csr_mt   = (int*)alloc(400000 * 4);
    int* csr_rev  = (int*)alloc(400000 * 4);
    // classifier aliases (dead buffers at that point)
    ushort_t* e1h = aggh;            ushort_t* e1l = aggl;            // [20000][256]
    ushort_t* e2h = yh_dis;          ushort_t* e2l = yl_dis;          // [20000][128]
    float*    e3  = (float*)yh_drug;                                  // [20000][64] f32

    hipMemsetAsync(cnts, 0, 80000 * sizeof(int), stream);

    // weight prep: transpose + hi/lo split
    const float* wfam[4] = { Wl_mt, Wr_mt, Wl_rev, Wr_rev };
    ushort_t* wth[4] = { wlmt_h, wrmt_h, wlrev_h, wrrev_h };
    ushort_t* wtl[4] = { wlmt_l, wrmt_l, wlrev_l, wrrev_l };
    for (int f = 0; f < 4; ++f)
        for (int l = 0; l < NLAYERS; ++l)
            k_trans<<<dim3(4, 4), 256, 0, stream>>>(wfam[f] + (size_t)l * 65536,
                                                    wth[f] + (size_t)l * 65536,
                                                    wtl[f] + (size_t)l * 65536, 256, 256);
    k_trans<<<dim3(4, 8), 256, 0, stream>>>(fc1_w, fc1t_h, fc1t_l, 512, 256);
    k_trans<<<dim3(2, 4), 256, 0, stream>>>(fc2_w, fc2t_h, fc2t_l, 256, 128);
    k_trans<<<dim3(1, 2), 256, 0, stream>>>(fc3_w, fc3t_h, fc3t_l, 128, 64);

    k_init<<<NDRUG, HID, 0, stream>>>(drug_id, drug_emb, disease_x, lin_w, lin_b,
                                      dis_id, dis_emb, xh_drug, xl_drug, xh_dis, xl_dis);
    int nbE = (NE + 255) / 256;
    k_count<<<nbE, 256, 0, stream>>>(e_mt + NE, NE, cnt_dis);
    k_count<<<nbE, 256, 0, stream>>>(e_rev + NE, NE, cnt_drug);
    k_scan<<<2, 1024, 0, stream>>>(cnt_dis, off_dis, cnt_drug, off_drug, 20000);
    k_fill<<<nbE, 256, 0, stream>>>(e_mt, e_mt + NE, NE, off_dis, cur_dis, csr_mt);
    k_fill<<<nbE, 256, 0, stream>>>(e_rev, e_rev + NE, NE, off_drug, cur_drug, csr_rev);

    ushort_t *xdh = xh_dis, *xdl = xl_dis, *xgh = xh_drug, *xgl = xl_drug;
    ushort_t *tdh = yh_dis, *tdl = yl_dis, *tgh = yh_drug, *tgl = yl_drug;
    dim3 gL(157, 4);
    for (int l = 0; l < NLAYERS; ++l) {
        int relu = (l < NLAYERS - 1) ? 1 : 0;
        size_t wo = (size_t)l * 65536;
        // disease side: agg over may_treat (drug->disease), then h_dis
        k_agg<<<NDIS, 128, 0, stream>>>((const uint_t*)xgh, off_dis, csr_mt,
                                        (uint_t*)aggh, (uint_t*)aggl);
        k_mgemm<2, 0><<<gL, 256, 0, stream>>>(
            aggh, aggl, xdh, xdl, nullptr, nullptr, 0,
            wlmt_h + wo, wlmt_l + wo, wrmt_h + wo, wrmt_l + wo, 256, 0,
            bl_mt + l * HID, NDIS, 256, 256, relu, tdh, tdl, nullptr);
        // drug side: agg over rev (disease->drug), then h_drug (xdh still intact)
        k_agg<<<NDRUG, 128, 0, stream>>>((const uint_t*)xdh, off_drug, csr_rev,
                                         (uint_t*)aggh, (uint_t*)aggl);
        k_mgemm<2, 0><<<gL, 256, 0, stream>>>(
            aggh, aggl, xgh, xgl, nullptr, nullptr, 0,
            wlrev_h + wo, wlrev_l + wo, wrrev_h + wo, wrrev_l + wo, 256, 0,
            bl_rev + l * HID, NDRUG, 256, 256, relu, tgh, tgl, nullptr);
        ushort_t* t;
        t = xdh; xdh = tdh; tdh = t;  t = xdl; xdl = tdl; tdl = t;
        t = xgh; xgh = tgh; tgh = t;  t = xgl; xgl = tgl; tgl = t;
    }

    // classifier, 5 chunks of 20000 label edges
    for (int c = 0; c < NEL; c += 20000) {
        int Mc = 20000;
        k_mgemm<2, 1><<<dim3(157, 4), 256, 0, stream>>>(
            xgh, xgl, xdh, xdl, e_lbl, e_lbl + NEL, c,
            fc1t_h, fc1t_l, fc1t_h, fc1t_l, 512, 256,
            fc1_b, Mc, 256, 256, 1, e1h, e1l, nullptr);
        k_mgemm<1, 0><<<dim3(157, 2), 256, 0, stream>>>(
            e1h, e1l, nullptr, nullptr, nullptr, nullptr, 0,
            fc2t_h, fc2t_l, nullptr, nullptr, 256, 0,
            fc2_b, Mc, 128, 256, 1, e2h, e2l, nullptr);
        k_mgemm<1, 0><<<dim3(157, 1), 256, 0, stream>>>(
            e2h, e2l, nullptr, nullptr, nullptr, nullptr, 0,
            fc3t_h, fc3t_l, nullptr, nullptr, 128, 0,
            fc3_b, Mc, 64, 128, 1, nullptr, nullptr, e3);
        k_fc4<<<(Mc + 3) / 4, 256, 0, stream>>>(e3, fc4_w, fc4_b, out + c, Mc);
    }
}